// Round 4
// baseline (237.635 us; speedup 1.0000x reference)
//
#include <hip/hip_runtime.h>
#include <hip/hip_bf16.h>

// Problem dims (fixed by reference)
#define BATCH 128
#define PIX   196
#define EDIM  2048
#define DDIM  512
#define ADIM  512
#define MTOT  (BATCH*PIX)   // 25088
#define BK    32
#define NK    (EDIM/BK)     // 64
#define NSLC  4             // N split: 4 slices of 128
#define BN    128
#define BM    128

typedef __attribute__((ext_vector_type(8))) short short8;
typedef __attribute__((ext_vector_type(4))) float f32x4;

__device__ __forceinline__ unsigned short f2bf(float f) {
    union { float f; unsigned int u; } c; c.f = f;
    unsigned int u = c.u;
    u += 0x7fffu + ((u >> 16) & 1u);   // round-to-nearest-even
    return (unsigned short)(u >> 16);
}

// Hardware cvt (compiler emits v_cvt_pk_bf16_f32; RNE, matches f2bf)
__device__ __forceinline__ short8 cvt8(float4 a, float4 b) {
    short8 v;
    v[0] = (short)__bfloat16_as_ushort(__float2bfloat16(a.x));
    v[1] = (short)__bfloat16_as_ushort(__float2bfloat16(a.y));
    v[2] = (short)__bfloat16_as_ushort(__float2bfloat16(a.z));
    v[3] = (short)__bfloat16_as_ushort(__float2bfloat16(a.w));
    v[4] = (short)__bfloat16_as_ushort(__float2bfloat16(b.x));
    v[5] = (short)__bfloat16_as_ushort(__float2bfloat16(b.y));
    v[6] = (short)__bfloat16_as_ushort(__float2bfloat16(b.z));
    v[7] = (short)__bfloat16_as_ushort(__float2bfloat16(b.w));
    return v;
}

#define GLOAD16(gp, lp) __builtin_amdgcn_global_load_lds( \
    (const __attribute__((address_space(1))) void*)(gp),  \
    (__attribute__((address_space(3))) void*)(lp), 16, 0, 0)

#define MFMA16(a, b, c) __builtin_amdgcn_mfma_f32_16x16x32_bf16(a, b, c, 0, 0, 0)

// ---------------------------------------------------------------------------
// Kernel 0: pack W_enc [K=2048][A=512] fp32 into per-(kt,ns) 8KB LDS images.
// Image (kt,ns), byte cl*16 (cl=0..511): j=cl>>6, nl16=(cl>>2)&15, kc=cl&3;
// holds bf16 of W_enc[kt*32 + kc*8 + d][ns*128 + j*16 + nl16], d=0..7.
// gemm slurps each image linearly; frag read j*1024 + cif*64 + rgrp*16.
// ---------------------------------------------------------------------------
__global__ __launch_bounds__(256) void pack_wenc(const float* __restrict__ Wenc,
                                                 unsigned short* __restrict__ WTp) {
    __shared__ float f[32 * ADIM];   // 64 KB: rows k=kt*32..+31
    const int kt = blockIdx.x;
    const int tid = threadIdx.x;
    const float4* src = (const float4*)(Wenc + (size_t)kt * 32 * ADIM);
    float4* dst = (float4*)f;
    #pragma unroll
    for (int i = 0; i < 16; ++i)
        dst[tid + i * 256] = src[tid + i * 256];
    __syncthreads();
    for (int c = tid; c < 2048; c += 256) {
        int ns   = c >> 9;
        int cl   = c & 511;
        int j    = cl >> 6;
        int nl16 = (cl >> 2) & 15;
        int kc   = cl & 3;
        int n    = ns * 128 + j * 16 + nl16;
        short8 v;
        #pragma unroll
        for (int d = 0; d < 8; ++d)
            v[d] = (short)f2bf(f[(kc * 8 + d) * ADIM + n]);
        *(short8*)(WTp + (size_t)kt * 16384 + (size_t)c * 8) = v;
    }
}

// ---------------------------------------------------------------------------
// Kernel 1: bias[b][a] = sum_d dec[b][d]*Wdec[d][a] + b_dec[a] + b_enc[a]
// ---------------------------------------------------------------------------
__global__ __launch_bounds__(256) void bias_kernel(const float* __restrict__ dec,
                                                   const float* __restrict__ Wdec,
                                                   const float* __restrict__ b_enc,
                                                   const float* __restrict__ b_dec,
                                                   float* __restrict__ bias) {
    __shared__ float ds[4 * DDIM];
    const int b0 = blockIdx.x * 4;
    for (int i = threadIdx.x; i < 4 * DDIM; i += 256)
        ds[i] = dec[(size_t)b0 * DDIM + i];
    __syncthreads();
    const int a0 = threadIdx.x * 2;
    float acc0[4] = {0.f, 0.f, 0.f, 0.f};
    float acc1[4] = {0.f, 0.f, 0.f, 0.f};
    for (int d = 0; d < DDIM; d++) {
        float2 w = *(const float2*)&Wdec[(size_t)d * ADIM + a0];
        #pragma unroll
        for (int bi = 0; bi < 4; bi++) {
            float dv = ds[bi * DDIM + d];
            acc0[bi] += dv * w.x;
            acc1[bi] += dv * w.y;
        }
    }
    float be0 = b_enc[a0] + b_dec[a0];
    float be1 = b_enc[a0 + 1] + b_dec[a0 + 1];
    #pragma unroll
    for (int bi = 0; bi < 4; bi++) {
        bias[(size_t)(b0 + bi) * ADIM + a0]     = acc0[bi] + be0;
        bias[(size_t)(b0 + bi) * ADIM + a0 + 1] = acc1[bi] + be1;
    }
}

// ---------------------------------------------------------------------------
// Kernel 2: fused att1 GEMM + relu + dot(W_full) -> att_part[ns][m]
// Block = 128M x 128N x fullK, 2 waves (2M), wave tile 64x128.
// 784 blocks (196 M-groups x 4 N-slices) -> ~3 blocks/CU TLP.
// B: pre-packed images via global_load_lds, ring-2 (16 KB LDS total).
// A: direct global->reg (fp32), cvt->bf16 at use; 1-iter lookahead.
// Counted vmcnt: loop never drains (vmcnt(4) / vmcnt(8) choreography).
// ---------------------------------------------------------------------------
__global__ __launch_bounds__(128, 2) void gemm_att(const float* __restrict__ enc,
                                                   const unsigned short* __restrict__ WTp,
                                                   const float* __restrict__ bias,
                                                   const float* __restrict__ Wfull,
                                                   float* __restrict__ att_part) {
    __shared__ __align__(16) char ldsB[2][8192];

    const int tid  = threadIdx.x;
    const int lane = tid & 63;
    const int wid  = tid >> 6;          // 0..1 = M-wave
    const int cif  = lane & 15;
    const int rgrp = lane >> 4;
    const int bid  = blockIdx.x;
    const int ns   = bid & 3;
    const int m0   = (bid >> 2) * BM;

    // B: linear image copy; this block's image stream for slice ns
    const char* pB = (const char*)WTp + (size_t)ns * 8192 + (size_t)wid * 4096
                   + (size_t)lane * 16;
    const unsigned bOff = (unsigned)(wid * 4096 + lane * 16);

    // A: per-lane frag rows (row = m0 + wid*64 + i*16 + cif, k-chunk rgrp)
    const float* pA[4];
    #pragma unroll
    for (int i = 0; i < 4; ++i)
        pA[i] = enc + (size_t)(m0 + wid * 64 + i * 16 + cif) * EDIM + rgrp * 8;

    char* bR = ldsB[0];
    char* bW = ldsB[1];

    f32x4 acc[4][8] = {};
    float4 areg[8];
    short8 ac[4];

    // ---- prologue: B(0) gloads, A(0) reg loads, wait B(0), publish ----
    #pragma unroll
    for (int c = 0; c < 4; ++c)
        GLOAD16(pB + c * 1024, bR + bOff + c * 1024);
    #pragma unroll
    for (int i = 0; i < 4; ++i) {
        areg[2 * i]     = *(const float4*)pA[i];
        areg[2 * i + 1] = *(const float4*)(pA[i] + 4);
    }
    asm volatile("s_waitcnt vmcnt(8)" ::: "memory");   // B(0) done; A(0) in flight
    __builtin_amdgcn_s_barrier();
    __builtin_amdgcn_sched_barrier(0);

    // ---- main loop kt = 0 .. NK-2 ----
    #pragma unroll 2
    for (int kt = 0; kt < NK - 1; ++kt) {
        // 1. issue B(kt+1) into write buffer (stays in flight across this iter)
        const char* ps = pB + (size_t)(kt + 1) * 32768;
        #pragma unroll
        for (int c = 0; c < 4; ++c)
            GLOAD16(ps + c * 1024, bW + bOff + c * 1024);
        // 2. A(kt) has landed (8 newest = nothing; 4 newest = B(kt+1))
        asm volatile("s_waitcnt vmcnt(4)" ::: "memory");
        #pragma unroll
        for (int i = 0; i < 4; ++i)
            ac[i] = cvt8(areg[2 * i], areg[2 * i + 1]);
        // 3. issue A(kt+1) reg loads (in flight across barrier)
        #pragma unroll
        for (int i = 0; i < 4; ++i) {
            const float* pa = pA[i] + (size_t)(kt + 1) * BK;
            areg[2 * i]     = *(const float4*)pa;
            areg[2 * i + 1] = *(const float4*)(pa + 4);
        }
        // 4. compute kt
        {
            short8 b[8];
            #pragma unroll
            for (int j = 0; j < 8; ++j)
                b[j] = *(const short8*)(bR + j * 1024 + cif * 64 + rgrp * 16);
            __builtin_amdgcn_s_setprio(1);
            #pragma unroll
            for (int i = 0; i < 4; ++i)
                #pragma unroll
                for (int j = 0; j < 8; ++j)
                    acc[i][j] = MFMA16(ac[i], b[j], acc[i][j]);
            __builtin_amdgcn_s_setprio(0);
        }
        // 5. publish kt+1: B(kt+1) retired, A(kt+1) 8 loads stay in flight
        asm volatile("s_waitcnt vmcnt(8) lgkmcnt(0)" ::: "memory");
        __builtin_amdgcn_s_barrier();
        __builtin_amdgcn_sched_barrier(0);
        { char* t = bR; bR = bW; bW = t; }
    }

    // ---- peeled kt = NK-1 ----
    asm volatile("s_waitcnt vmcnt(0)" ::: "memory");
    #pragma unroll
    for (int i = 0; i < 4; ++i)
        ac[i] = cvt8(areg[2 * i], areg[2 * i + 1]);
    {
        short8 b[8];
        #pragma unroll
        for (int j = 0; j < 8; ++j)
            b[j] = *(const short8*)(bR + j * 1024 + cif * 64 + rgrp * 16);
        #pragma unroll
        for (int i = 0; i < 4; ++i)
            #pragma unroll
            for (int j = 0; j < 8; ++j)
                acc[i][j] = MFMA16(ac[i], b[j], acc[i][j]);
    }

    // ---- epilogue: relu(acc + bias) . Wfull over this slice's 128 a-cols ----
    const int bf  = m0 / PIX;
    const int thr = (bf + 1) * PIX;
    const int bfc = (bf + 1 < BATCH) ? bf + 1 : BATCH - 1;
    float wf[8], bs0[8], bs1[8];
    #pragma unroll
    for (int j = 0; j < 8; ++j) {
        int aj = ns * 128 + j * 16 + cif;
        wf[j]  = Wfull[aj];
        bs0[j] = bias[(size_t)bf  * ADIM + aj];
        bs1[j] = bias[(size_t)bfc * ADIM + aj];
    }
    #pragma unroll
    for (int i = 0; i < 4; ++i) {
        #pragma unroll
        for (int r = 0; r < 4; ++r) {
            int ml = wid * 64 + i * 16 + rgrp * 4 + r;
            int m  = m0 + ml;
            bool sec = (m >= thr);
            float s = 0.f;
            #pragma unroll
            for (int j = 0; j < 8; ++j) {
                float v = acc[i][j][r] + (sec ? bs1[j] : bs0[j]);
                s += fmaxf(v, 0.f) * wf[j];
            }
            s += __shfl_xor(s, 1);
            s += __shfl_xor(s, 2);
            s += __shfl_xor(s, 4);
            s += __shfl_xor(s, 8);
            if (cif == 0) att_part[(size_t)ns * MTOT + m] = s;
        }
    }
}

// ---------------------------------------------------------------------------
// Kernel 3: softmax over p; att = sum of 4 N-slice partials (b_full cancels)
// ---------------------------------------------------------------------------
__global__ __launch_bounds__(256) void softmax_kernel(const float* __restrict__ att_part,
                                                      float* __restrict__ alpha) {
    const int b = blockIdx.x;
    const int tid = threadIdx.x;
    const int lane = tid & 63, wid = tid >> 6;
    __shared__ float wred[4];

    float x = -1e30f;
    if (tid < PIX) {
        size_t m = (size_t)b * PIX + tid;
        x = att_part[m] + att_part[MTOT + m] + att_part[2 * MTOT + m]
          + att_part[3 * MTOT + m];
    }
    float mx = x;
    #pragma unroll
    for (int off = 32; off >= 1; off >>= 1) mx = fmaxf(mx, __shfl_xor(mx, off));
    if (lane == 0) wred[wid] = mx;
    __syncthreads();
    float gm = fmaxf(fmaxf(wred[0], wred[1]), fmaxf(wred[2], wred[3]));
    __syncthreads();

    float e = (tid < PIX) ? __expf(x - gm) : 0.f;
    float s = e;
    #pragma unroll
    for (int off = 32; off >= 1; off >>= 1) s += __shfl_xor(s, off);
    if (lane == 0) wred[wid] = s;
    __syncthreads();
    float gs = wred[0] + wred[1] + wred[2] + wred[3];

    if (tid < PIX) alpha[(size_t)b * PIX + tid] = e / gs;
}

// ---------------------------------------------------------------------------
// Kernel 4: out[b][e] = sum_p enc[b][p][e] * alpha[b][p]
// ---------------------------------------------------------------------------
__global__ __launch_bounds__(128) void weighted_kernel(const float* __restrict__ enc,
                                                       const float* __restrict__ alpha,
                                                       float* __restrict__ out) {
    const int b = blockIdx.x >> 2;
    const int q = blockIdx.x & 3;
    const int tid = threadIdx.x;
    __shared__ float al[PIX];
    for (int i = tid; i < PIX; i += 128) al[i] = alpha[(size_t)b * PIX + i];
    __syncthreads();

    const int e = q * 512 + tid * 4;
    const float4* src = (const float4*)(enc + (size_t)b * PIX * EDIM + e);
    float ax = 0.f, ay = 0.f, az = 0.f, aw = 0.f;
    #pragma unroll 4
    for (int p = 0; p < PIX; p++) {
        float av = al[p];
        float4 v = src[(size_t)p * (EDIM / 4)];
        ax += av * v.x; ay += av * v.y; az += av * v.z; aw += av * v.w;
    }
    float4 o; o.x = ax; o.y = ay; o.z = az; o.w = aw;
    *(float4*)&out[(size_t)b * EDIM + e] = o;
}

// ---------------------------------------------------------------------------
extern "C" void kernel_launch(void* const* d_in, const int* in_sizes, int n_in,
                              void* d_out, int out_size, void* d_ws, size_t ws_size,
                              hipStream_t stream) {
    const float* enc   = (const float*)d_in[0];   // [128,196,2048]
    const float* dec   = (const float*)d_in[1];   // [128,512]
    const float* Wenc  = (const float*)d_in[2];   // [2048,512]
    const float* benc  = (const float*)d_in[3];   // [512]
    const float* Wdec  = (const float*)d_in[4];   // [512,512]
    const float* bdec  = (const float*)d_in[5];   // [512]
    const float* Wfull = (const float*)d_in[6];   // [512]
    // d_in[7] = b_full: constant shift, cancels in softmax

    float* out_awe   = (float*)d_out;                       // [128,2048]
    float* out_alpha = (float*)d_out + BATCH * EDIM;        // [128,196]

    char* ws = (char*)d_ws;
    unsigned short* WTp = (unsigned short*)ws;                      // 2 MB packed images
    float* bias = (float*)(ws + (size_t)ADIM * EDIM * 2);           // 256 KB [128][512]
    float* att_part = (float*)(ws + (size_t)ADIM * EDIM * 2
                             + (size_t)BATCH * ADIM * 4);           // 4 x 100 KB

    pack_wenc<<<NK, 256, 0, stream>>>(Wenc, WTp);
    bias_kernel<<<BATCH / 4, 256, 0, stream>>>(dec, Wdec, benc, bdec, bias);
    gemm_att<<<(MTOT / BM) * NSLC, 128, 0, stream>>>(enc, WTp, bias, Wfull, att_part);
    softmax_kernel<<<BATCH, 256, 0, stream>>>(att_part, out_alpha);
    weighted_kernel<<<BATCH * 4, 128, 0, stream>>>(enc, out_alpha, out_awe);
}